// Round 1
// baseline (729.081 us; speedup 1.0000x reference)
//
#include <hip/hip_runtime.h>
#include <hip/hip_bf16.h>

#define N_NODES 200000
#define N_GRAPHS 1024
#define D 16
#define NEDGE 6400000

#define BNODES 256                 // nodes per bucket: bucket = dst >> 8
#define NBUK 782                   // ceil(200000/256)
#define NCH 512                    // edge chunks
#define ECHUNK 12500               // NEDGE / NCH (exact)
#define OSTRIDE (NBUK + 1)         // 783
#define CAP 9216                   // bucket slab capacity (mean 8192, sd ~90 -> 11 sigma)
#define GBLK 12500                 // t1 blocks: 16 nodes x 16 lanes

// gather kernels: 64 nodes/block (4 lanes/node), split-D (8 features/pass).
// XCD partition: bid&7 -> XCD (round-robin dispatch); XCD 0-3 = R, 4-7 = L,
// so each per-XCD 4MB L2 holds exactly one 3.2MB half-feature table.
#define GQ 782
#define GGRID (GQ * 8)             // 6256
#define GBH 3125                   // 64-node blocks per protein (200000/64 exact)

// ---- pA (fused R+L): sort one 12500-edge chunk by bucket in LDS, coalesced writeback ----
__global__ __launch_bounds__(1024) void pA(
        const int* __restrict__ srcR, const int* __restrict__ dstR,
        const int* __restrict__ srcL, const int* __restrict__ dstL,
        unsigned int* __restrict__ slabC_R, unsigned int* __restrict__ slabC_L,
        int* __restrict__ offsT_R, int* __restrict__ offsT_L) {
    const int* src = blockIdx.y ? srcL : srcR;
    const int* dst = blockIdx.y ? dstL : dstR;
    unsigned int* slabC = blockIdx.y ? slabC_L : slabC_R;
    int* offsT = blockIdx.y ? offsT_L : offsT_R;

    __shared__ unsigned int stage[ECHUNK];   // 50 KB
    __shared__ int lh[NBUK];
    __shared__ int lcur[NBUK];
    __shared__ int wsum[16];
    int t = threadIdx.x;
    int wave = t >> 6, lane = t & 63;
    int c = blockIdx.x;
    int base = c * ECHUNK;

    for (int k = t; k < NBUK; k += 1024) lh[k] = 0;
    __syncthreads();
    for (int e = t; e < ECHUNK; e += 1024)
        atomicAdd(&lh[((unsigned int)dst[base + e]) >> 8], 1);
    __syncthreads();

    int v = (t < NBUK) ? lh[t] : 0;
    int x = v;
#pragma unroll
    for (int d0 = 1; d0 < 64; d0 <<= 1) {
        int y = __shfl_up(x, d0, 64);
        if (lane >= d0) x += y;
    }
    if (lane == 63) wsum[wave] = x;
    __syncthreads();
    if (wave == 0 && lane < 16) {
        int s = wsum[lane];
#pragma unroll
        for (int d0 = 1; d0 < 16; d0 <<= 1) {
            int y = __shfl_up(s, d0, 64);
            if (lane >= d0) s += y;
        }
        wsum[lane] = s;
    }
    __syncthreads();
    int excl = x - v + (wave ? wsum[wave - 1] : 0);
    if (t < NBUK) lcur[t] = excl;
    __syncthreads();

    for (int e = t; e < ECHUNK; e += 1024) {
        int d = dst[base + e];
        int s = src[base + e];
        int pos = atomicAdd(&lcur[d >> 8], 1);
        stage[pos] = ((unsigned int)(d & 255) << 18) | (unsigned int)s;
    }
    __syncthreads();
    for (int e = t; e < ECHUNK; e += 1024) slabC[base + e] = stage[e];
    if (t < NBUK) offsT[c * OSTRIDE + t] = excl;
    if (t == 0) offsT[c * OSTRIDE + NBUK] = ECHUNK;
}

// ---- transpose offsT [NCH][OSTRIDE] -> offsTT [OSTRIDE][NCH] ----
__global__ __launch_bounds__(256) void tr_kernel(
        const int* __restrict__ offsT_R, const int* __restrict__ offsT_L,
        int* __restrict__ offsTT_R, int* __restrict__ offsTT_L) {
    const int* in = blockIdx.z ? offsT_L : offsT_R;
    int* outp = blockIdx.z ? offsTT_L : offsTT_R;
    __shared__ int tile[32][33];
    int lx = threadIdx.x & 31, ly = threadIdx.x >> 5;   // 32 x 8
#pragma unroll
    for (int r = 0; r < 32; r += 8) {
        int row = blockIdx.y * 32 + ly + r;             // chunk index (<512 exact)
        int col = blockIdx.x * 32 + lx;                 // OSTRIDE index
        if (col < OSTRIDE) tile[ly + r][lx] = in[row * OSTRIDE + col];
    }
    __syncthreads();
#pragma unroll
    for (int r = 0; r < 32; r += 8) {
        int orow = blockIdx.x * 32 + ly + r;            // OSTRIDE index
        int ocol = blockIdx.y * 32 + lx;                // chunk index
        if (orow < OSTRIDE) outp[orow * NCH + ocol] = tile[lx][ly + r];
    }
}

// ---- pB (fused R+L): single-pass per-bucket counting sort (LDS-staged input) ----
__global__ __launch_bounds__(256) void pB(
        const unsigned int* __restrict__ slabC_R, const unsigned int* __restrict__ slabC_L,
        const int* __restrict__ offsTT_R, const int* __restrict__ offsTT_L,
        unsigned int* __restrict__ slabR, unsigned int* __restrict__ slabL,
        int2* __restrict__ metaR, int2* __restrict__ metaL,
        float* __restrict__ disR, float* __restrict__ disL) {
    int y = blockIdx.y;
    const unsigned int* slabC = y ? slabC_L : slabC_R;
    const int* offsTT = y ? offsTT_L : offsTT_R;
    unsigned int* slab = y ? slabL : slabR;
    int2* meta = y ? metaL : metaR;
    float* dis = y ? disL : disR;

    __shared__ unsigned int sin_[CAP];       // 36.9 KB
    __shared__ unsigned int sout[CAP];       // 36.9 KB
    __shared__ int hcnt[BNODES], hoff[BNODES], hcur[BNODES];
    __shared__ int wtot[4];
    __shared__ int totc;
    int t = threadIdx.x;
    int lane = t & 63, wave = t >> 6;
    int b = blockIdx.x;

    // run bounds for this thread's two chunks (coalesced row reads of offsTT)
    int a0 = offsTT[b * NCH + t],        e0 = offsTT[(b + 1) * NCH + t];
    int a1 = offsTT[b * NCH + t + 256],  e1 = offsTT[(b + 1) * NCH + t + 256];
    int len = (e0 - a0) + (e1 - a1);

    // block exclusive scan of len -> sbase
    int x = len;
#pragma unroll
    for (int d0 = 1; d0 < 64; d0 <<= 1) {
        int yy = __shfl_up(x, d0, 64);
        if (lane >= d0) x += yy;
    }
    if (lane == 63) wtot[wave] = x;
    hcnt[t] = 0;
    __syncthreads();
    int pre = 0;
    for (int w2 = 0; w2 < wave; w2++) pre += wtot[w2];
    int sbase = x - len + pre;
    if (t == 255) totc = sbase + len;
    __syncthreads();

    // stage both runs into sin_ (vectorized uint4 reads)
    int p = sbase;
    {
        int cb = t * ECHUNK;
        for (int i = (a0 & ~3); i < e0; i += 4) {
            uint4 v = *(const uint4*)(slabC + cb + i);
            unsigned int vv[4] = {v.x, v.y, v.z, v.w};
#pragma unroll
            for (int k = 0; k < 4; k++) {
                int idx = i + k;
                if (idx >= a0 && idx < e0) { if (p < CAP) sin_[p] = vv[k]; p++; }
            }
        }
        cb = (t + 256) * ECHUNK;
        for (int i = (a1 & ~3); i < e1; i += 4) {
            uint4 v = *(const uint4*)(slabC + cb + i);
            unsigned int vv[4] = {v.x, v.y, v.z, v.w};
#pragma unroll
            for (int k = 0; k < 4; k++) {
                int idx = i + k;
                if (idx >= a1 && idx < e1) { if (p < CAP) sin_[p] = vv[k]; p++; }
            }
        }
    }
    __syncthreads();
    int cnt = totc;
    if (cnt > CAP) cnt = CAP;   // statistically unreachable

    // count
    for (int i = t; i < cnt; i += 256) atomicAdd(&hcnt[sin_[i] >> 18], 1);
    __syncthreads();

    // exclusive scan of hcnt
    int v2 = hcnt[t];
    int x2 = v2;
#pragma unroll
    for (int d0 = 1; d0 < 64; d0 <<= 1) {
        int yy = __shfl_up(x2, d0, 64);
        if (lane >= d0) x2 += yy;
    }
    if (lane == 63) wtot[wave] = x2;
    __syncthreads();
    int pre2 = 0;
    for (int w2 = 0; w2 < wave; w2++) pre2 += wtot[w2];
    int ex = x2 - v2 + pre2;
    hoff[t] = ex;
    hcur[t] = ex;
    __syncthreads();

    // place
    for (int i = t; i < cnt; i += 256) {
        unsigned int r = sin_[i];
        int pp = atomicAdd(&hcur[r >> 18], 1);
        if (pp < CAP) sout[pp] = r & 0x3FFFFu;
    }
    __syncthreads();

    int gb = b * CAP;
    for (int i = t; i < cnt; i += 256) slab[gb + i] = sout[i];   // coalesced
    int node = (b << 8) + t;
    if (node < N_NODES) {
        meta[node] = make_int2(gb + hoff[t], gb + hoff[t] + hcnt[t]);
        dis[node] = rsqrtf((float)hcnt[t] + 1.0f);
    }
}

// ---- t1 (fused R+L): hs1[i,j] = bf16( (emb[ids[i]] @ W1)[j] * dis[i] ), split-D layout ----
__global__ __launch_bounds__(256) void t1_kernel(
        const int* __restrict__ idsR, const int* __restrict__ idsL,
        const float* __restrict__ emb, const float* __restrict__ W,
        const float* __restrict__ disR, const float* __restrict__ disL,
        __hip_bfloat16* __restrict__ h1aR, __hip_bfloat16* __restrict__ h1bR,
        __hip_bfloat16* __restrict__ h1aL, __hip_bfloat16* __restrict__ h1bL) {
    int y = blockIdx.y;
    const int* ids = y ? idsL : idsR;
    const float* dis = y ? disL : disR;
    __hip_bfloat16* ha = y ? h1aL : h1aR;
    __hip_bfloat16* hb = y ? h1bL : h1bR;
    __shared__ float sW[D][D];
    __shared__ float sx[16][D + 1];
    int t = threadIdx.x;
    int j = t & 15, g = t >> 4;
    sW[g][j] = W[t];
    int i = (blockIdx.x << 4) + g;
    sx[g][j] = emb[(size_t)ids[i] * D + j];
    __syncthreads();
    float acc = 0.f;
#pragma unroll
    for (int k = 0; k < D; k++) acc += sx[g][k] * sW[k][j];
    __hip_bfloat16 v = __float2bfloat16(acc * dis[i]);
    if (j < 8) ha[(size_t)i * 8 + j] = v;
    else       hb[(size_t)i * 8 + (j - 8)] = v;
}

// ---- G1a: gather features 0-7 of hs1, relu epilogue -> xA (bf16 [N][8]) ----
__global__ __launch_bounds__(256) void g1a_kernel(
        const int2* __restrict__ metaR, const int2* __restrict__ metaL,
        const unsigned int* __restrict__ csrR, const unsigned int* __restrict__ csrL,
        const __hip_bfloat16* __restrict__ haR, const __hip_bfloat16* __restrict__ haL,
        const float* __restrict__ disR, const float* __restrict__ disL,
        const float* __restrict__ b1,
        __hip_bfloat16* __restrict__ xAR, __hip_bfloat16* __restrict__ xAL) {
    int bid = blockIdx.x;
    int rr = bid & 7;                 // XCD (round-robin dispatch assumption)
    int half = rr >> 2;               // XCD 0-3 = R, 4-7 = L
    int bx = (bid >> 3) * 4 + (rr & 3);
    if (bx >= GBH) return;
    const int2* meta = half ? metaL : metaR;
    const unsigned int* csr = half ? csrL : csrR;
    const __hip_bfloat16* ha = half ? haL : haR;
    const float* dis = half ? disL : disR;
    __hip_bfloat16* xA = half ? xAL : xAR;

    int t = threadIdx.x;
    int jp = t & 3, g = t >> 2;
    int i = (bx << 6) + g;
    int2 be = meta[i];
    float2 acc = __bfloat1622float2(*(const __hip_bfloat162*)(ha + (size_t)i * 8 + 2 * jp));
    int e = be.x, end = be.y;
    for (; e + 8 <= end; e += 8) {
        int m0 = (int)__builtin_nontemporal_load(csr + e + jp);
        int m1 = (int)__builtin_nontemporal_load(csr + e + 4 + jp);
#pragma unroll
        for (int n = 0; n < 4; n++) {
            int s = __shfl(m0, n, 4);
            float2 f = __bfloat1622float2(*(const __hip_bfloat162*)(ha + (size_t)s * 8 + 2 * jp));
            acc.x += f.x; acc.y += f.y;
        }
#pragma unroll
        for (int n = 0; n < 4; n++) {
            int s = __shfl(m1, n, 4);
            float2 f = __bfloat1622float2(*(const __hip_bfloat162*)(ha + (size_t)s * 8 + 2 * jp));
            acc.x += f.x; acc.y += f.y;
        }
    }
    for (; e < end; e++) {
        int s = (int)csr[e];
        float2 f = __bfloat1622float2(*(const __hip_bfloat162*)(ha + (size_t)s * 8 + 2 * jp));
        acc.x += f.x; acc.y += f.y;
    }
    float di = dis[i];
    float2 xa;
    xa.x = fmaxf(acc.x * di + b1[2 * jp], 0.f);
    xa.y = fmaxf(acc.y * di + b1[2 * jp + 1], 0.f);
    *(__hip_bfloat162*)(xA + (size_t)i * 8 + 2 * jp) = __float22bfloat162_rn(xa);
}

// ---- G1b: gather features 8-15 of hs1, combine with xA, W2 transform -> hs2a/hs2b ----
__global__ __launch_bounds__(256) void g1b_kernel(
        const int2* __restrict__ metaR, const int2* __restrict__ metaL,
        const unsigned int* __restrict__ csrR, const unsigned int* __restrict__ csrL,
        const __hip_bfloat16* __restrict__ hbR, const __hip_bfloat16* __restrict__ hbL,
        const __hip_bfloat16* __restrict__ xAR, const __hip_bfloat16* __restrict__ xAL,
        const float* __restrict__ disR, const float* __restrict__ disL,
        const float* __restrict__ b1, const float* __restrict__ W2,
        __hip_bfloat16* __restrict__ h2aR, __hip_bfloat16* __restrict__ h2bR,
        __hip_bfloat16* __restrict__ h2aL, __hip_bfloat16* __restrict__ h2bL) {
    int bid = blockIdx.x;
    int rr = bid & 7;
    int half = rr >> 2;
    int bx = (bid >> 3) * 4 + (rr & 3);
    if (bx >= GBH) return;
    const int2* meta = half ? metaL : metaR;
    const unsigned int* csr = half ? csrL : csrR;
    const __hip_bfloat16* hb = half ? hbL : hbR;
    const __hip_bfloat16* xA = half ? xAL : xAR;
    const float* dis = half ? disL : disR;
    __hip_bfloat16* h2a = half ? h2aL : h2aR;
    __hip_bfloat16* h2b = half ? h2bL : h2bR;

    __shared__ float sW[D][D];
    __shared__ float sx[64][D + 1];
    int t = threadIdx.x;
    sW[t >> 4][t & 15] = W2[t];
    int jp = t & 3, g = t >> 2;
    int i = (bx << 6) + g;
    int2 be = meta[i];
    float2 acc = __bfloat1622float2(*(const __hip_bfloat162*)(hb + (size_t)i * 8 + 2 * jp));
    int e = be.x, end = be.y;
    for (; e + 8 <= end; e += 8) {
        int m0 = (int)__builtin_nontemporal_load(csr + e + jp);
        int m1 = (int)__builtin_nontemporal_load(csr + e + 4 + jp);
#pragma unroll
        for (int n = 0; n < 4; n++) {
            int s = __shfl(m0, n, 4);
            float2 f = __bfloat1622float2(*(const __hip_bfloat162*)(hb + (size_t)s * 8 + 2 * jp));
            acc.x += f.x; acc.y += f.y;
        }
#pragma unroll
        for (int n = 0; n < 4; n++) {
            int s = __shfl(m1, n, 4);
            float2 f = __bfloat1622float2(*(const __hip_bfloat162*)(hb + (size_t)s * 8 + 2 * jp));
            acc.x += f.x; acc.y += f.y;
        }
    }
    for (; e < end; e++) {
        int s = (int)csr[e];
        float2 f = __bfloat1622float2(*(const __hip_bfloat162*)(hb + (size_t)s * 8 + 2 * jp));
        acc.x += f.x; acc.y += f.y;
    }
    float di = dis[i];
    unsigned int xabits = __builtin_nontemporal_load(
        (const unsigned int*)(xA + (size_t)i * 8 + 2 * jp));
    __hip_bfloat162 xav = *(__hip_bfloat162*)&xabits;
    float2 xa = __bfloat1622float2(xav);
    sx[g][2 * jp]     = xa.x;
    sx[g][2 * jp + 1] = xa.y;
    sx[g][8 + 2 * jp] = fmaxf(acc.x * di + b1[8 + 2 * jp], 0.f);
    sx[g][9 + 2 * jp] = fmaxf(acc.y * di + b1[9 + 2 * jp], 0.f);
    __syncthreads();
    float a0 = 0.f, a1 = 0.f, c0 = 0.f, c1 = 0.f;
#pragma unroll
    for (int k = 0; k < D; k++) {
        float xv = sx[g][k];
        a0 += xv * sW[k][2 * jp];
        a1 += xv * sW[k][2 * jp + 1];
        c0 += xv * sW[k][8 + 2 * jp];
        c1 += xv * sW[k][9 + 2 * jp];
    }
    *(__hip_bfloat162*)(h2a + (size_t)i * 8 + 2 * jp) =
        __float22bfloat162_rn(make_float2(a0 * di, a1 * di));
    *(__hip_bfloat162*)(h2b + (size_t)i * 8 + 2 * jp) =
        __float22bfloat162_rn(make_float2(c0 * di, c1 * di));
}

// ---- G2: gather layer2 half-features + fused mean-pool partial reduction.
//      blockIdx.y = pass (0: features 0-7 from hs2a, 1: features 8-15 from hs2b) ----
__global__ __launch_bounds__(256) void g2_kernel(
        const int2* __restrict__ metaR, const int2* __restrict__ metaL,
        const unsigned int* __restrict__ csrR, const unsigned int* __restrict__ csrL,
        const __hip_bfloat16* __restrict__ h2aR, const __hip_bfloat16* __restrict__ h2bR,
        const __hip_bfloat16* __restrict__ h2aL, const __hip_bfloat16* __restrict__ h2bL,
        const float* __restrict__ disR, const float* __restrict__ disL,
        const float* __restrict__ b2,
        const int* __restrict__ batR, const int* __restrict__ batL,
        float* __restrict__ sumsR, float* __restrict__ sumsL,
        float* __restrict__ cntR, float* __restrict__ cntL) {
    int pass = blockIdx.y;
    int bid = blockIdx.x;
    int rr = bid & 7;
    int half = rr >> 2;
    int bx = (bid >> 3) * 4 + (rr & 3);
    if (bx >= GBH) return;
    const int2* meta = half ? metaL : metaR;
    const unsigned int* csr = half ? csrL : csrR;
    const __hip_bfloat16* tab = pass ? (half ? h2bL : h2bR) : (half ? h2aL : h2aR);
    const float* dis = half ? disL : disR;
    const int* batch = half ? batL : batR;
    float* sums = half ? sumsL : sumsR;
    float* cnt = half ? cntL : cntR;
    int off = pass << 3;

    __shared__ float sv[64][9];
    __shared__ int sb[64];
    int t = threadIdx.x;
    int jp = t & 3, g = t >> 2;
    int i = (bx << 6) + g;
    int2 be = meta[i];
    float2 acc = __bfloat1622float2(*(const __hip_bfloat162*)(tab + (size_t)i * 8 + 2 * jp));
    int e = be.x, end = be.y;
    for (; e + 8 <= end; e += 8) {
        int m0 = (int)__builtin_nontemporal_load(csr + e + jp);
        int m1 = (int)__builtin_nontemporal_load(csr + e + 4 + jp);
#pragma unroll
        for (int n = 0; n < 4; n++) {
            int s = __shfl(m0, n, 4);
            float2 f = __bfloat1622float2(*(const __hip_bfloat162*)(tab + (size_t)s * 8 + 2 * jp));
            acc.x += f.x; acc.y += f.y;
        }
#pragma unroll
        for (int n = 0; n < 4; n++) {
            int s = __shfl(m1, n, 4);
            float2 f = __bfloat1622float2(*(const __hip_bfloat162*)(tab + (size_t)s * 8 + 2 * jp));
            acc.x += f.x; acc.y += f.y;
        }
    }
    for (; e < end; e++) {
        int s = (int)csr[e];
        float2 f = __bfloat1622float2(*(const __hip_bfloat162*)(tab + (size_t)s * 8 + 2 * jp));
        acc.x += f.x; acc.y += f.y;
    }
    float di = dis[i];
    int bi = batch[i];
    sv[g][2 * jp]     = acc.x * di + b2[off + 2 * jp];
    sv[g][2 * jp + 1] = acc.y * di + b2[off + 2 * jp + 1];
    if (jp == 0) sb[g] = bi;
    __syncthreads();
    bool runend = (g == 63) || (sb[g + 1] != bi);
    if (runend) {
        float s0 = 0.f, s1 = 0.f;
        int gg = g;
        while (gg >= 0 && sb[gg] == bi) { s0 += sv[gg][2 * jp]; s1 += sv[gg][2 * jp + 1]; gg--; }
        atomicAdd(&sums[bi * D + off + 2 * jp], s0);
        atomicAdd(&sums[bi * D + off + 2 * jp + 1], s1);
        if (pass == 0 && jp == 0) atomicAdd(&cnt[bi], (float)(g - gg));
    }
}

// ---- final FC ----
__global__ void final_kernel(const float* __restrict__ rs, const float* __restrict__ rc,
                             const float* __restrict__ ls, const float* __restrict__ lc,
                             const float* __restrict__ fcW, const float* __restrict__ fcb,
                             float* __restrict__ out) {
    int b = blockIdx.x * blockDim.x + threadIdx.x;
    if (b >= N_GRAPHS) return;
    float hc[2 * D];
    float rn = fmaxf(rc[b], 1.f), ln = fmaxf(lc[b], 1.f);
#pragma unroll
    for (int j = 0; j < D; j++) {
        hc[j]     = rs[b * D + j] / rn;
        hc[D + j] = ls[b * D + j] / ln;
    }
#pragma unroll
    for (int c = 0; c < 6; c++) {
        float acc = fcb[c];
#pragma unroll
        for (int j = 0; j < 2 * D; j++) acc += hc[j] * fcW[c * 2 * D + j];
        if (c < 3) out[b * 3 + c] = acc;
        else       out[N_GRAPHS * 3 + b * 3 + (c - 3)] = acc;
    }
}

extern "C" void kernel_launch(void* const* d_in, const int* in_sizes, int n_in,
                              void* d_out, int out_size, void* d_ws, size_t ws_size,
                              hipStream_t stream) {
    const float* emb = (const float*)d_in[0];
    const float* W1  = (const float*)d_in[1];
    const float* b1  = (const float*)d_in[2];
    const float* W2  = (const float*)d_in[3];
    const float* b2  = (const float*)d_in[4];
    const float* fcW = (const float*)d_in[5];
    const float* fcb = (const float*)d_in[6];
    const int* rx = (const int*)d_in[7];
    const int* re = (const int*)d_in[8];
    const int* rb = (const int*)d_in[9];
    const int* lx = (const int*)d_in[10];
    const int* le = (const int*)d_in[11];
    const int* lb = (const int*)d_in[12];
    float* out = (float*)d_out;

    char* w = (char*)d_ws;
    // slabC region (51.2 MB total), dead after pB; split-D bf16 tables (10 x 3.2 MB = 32 MB)
    // overlay it.
    unsigned int* slabC_R = (unsigned int*)w;
    __hip_bfloat16* h1aR = (__hip_bfloat16*)w;
    __hip_bfloat16* h1bR = h1aR + (size_t)N_NODES * 8;
    __hip_bfloat16* h1aL = h1bR + (size_t)N_NODES * 8;
    __hip_bfloat16* h1bL = h1aL + (size_t)N_NODES * 8;
    __hip_bfloat16* h2aR = h1bL + (size_t)N_NODES * 8;
    __hip_bfloat16* h2bR = h2aR + (size_t)N_NODES * 8;
    __hip_bfloat16* h2aL = h2bR + (size_t)N_NODES * 8;
    __hip_bfloat16* h2bL = h2aL + (size_t)N_NODES * 8;
    __hip_bfloat16* xAR  = h2bL + (size_t)N_NODES * 8;
    __hip_bfloat16* xAL  = xAR  + (size_t)N_NODES * 8;
    w += (size_t)NEDGE * 4;
    unsigned int* slabC_L = (unsigned int*)w;  w += (size_t)NEDGE * 4;
    unsigned int* slabR = (unsigned int*)w;    w += (size_t)NBUK * CAP * 4;
    unsigned int* slabL = (unsigned int*)w;    w += (size_t)NBUK * CAP * 4;
    int* offsT_R = (int*)w;                    w += (size_t)NCH * OSTRIDE * 4;
    int* offsT_L = (int*)w;                    w += (size_t)NCH * OSTRIDE * 4;
    int* offsTT_R = (int*)w;                   w += (size_t)OSTRIDE * NCH * 4;
    int* offsTT_L = (int*)w;                   w += (size_t)OSTRIDE * NCH * 4;
    int2* metaR = (int2*)w;                    w += (size_t)N_NODES * 8;
    int2* metaL = (int2*)w;                    w += (size_t)N_NODES * 8;
    float* disR = (float*)w;                   w += (size_t)N_NODES * 4;
    float* disL = (float*)w;                   w += (size_t)N_NODES * 4;
    float* sums0 = (float*)w;                  w += (size_t)N_GRAPHS * D * 4;
    float* cnt0  = (float*)w;                  w += (size_t)N_GRAPHS * 4;
    float* sums1 = (float*)w;                  w += (size_t)N_GRAPHS * D * 4;
    float* cnt1  = (float*)w;                  w += (size_t)N_GRAPHS * 4;

    const int* srcR = re;  const int* dstR = re + NEDGE;
    const int* srcL = le;  const int* dstL = le + NEDGE;

    hipMemsetAsync(sums0, 0, ((size_t)N_GRAPHS * (D + 1)) * 2 * sizeof(float), stream);

    // ---- CSR build (R+L fused) ----
    pA<<<dim3(NCH, 2), 1024, 0, stream>>>(srcR, dstR, srcL, dstL,
                                          slabC_R, slabC_L, offsT_R, offsT_L);
    tr_kernel<<<dim3((OSTRIDE + 31) / 32, NCH / 32, 2), 256, 0, stream>>>(
        offsT_R, offsT_L, offsTT_R, offsTT_L);
    pB<<<dim3(NBUK, 2), 256, 0, stream>>>(slabC_R, slabC_L, offsTT_R, offsTT_L,
                                          slabR, slabL, metaR, metaL, disR, disL);

    // ---- fused GCN pipeline (split-D gathers, XCD-partitioned) ----
    t1_kernel<<<dim3(GBLK, 2), 256, 0, stream>>>(rx, lx, emb, W1, disR, disL,
                                                 h1aR, h1bR, h1aL, h1bL);
    g1a_kernel<<<GGRID, 256, 0, stream>>>(metaR, metaL, slabR, slabL,
                                          h1aR, h1aL, disR, disL, b1, xAR, xAL);
    g1b_kernel<<<GGRID, 256, 0, stream>>>(metaR, metaL, slabR, slabL,
                                          h1bR, h1bL, xAR, xAL, disR, disL, b1, W2,
                                          h2aR, h2bR, h2aL, h2bL);
    g2_kernel<<<dim3(GGRID, 2), 256, 0, stream>>>(metaR, metaL, slabR, slabL,
                                                  h2aR, h2bR, h2aL, h2bL,
                                                  disR, disL, b2, rb, lb,
                                                  sums0, sums1, cnt0, cnt1);
    final_kernel<<<(N_GRAPHS + 255) / 256, 256, 0, stream>>>(
        sums0, cnt0, sums1, cnt1, fcW, fcb, out);
}